// Round 20
// baseline (155.876 us; speedup 1.0000x reference)
//
#include <hip/hip_runtime.h>
#include <hip/hip_bf16.h>

#define HWA 4096
#define CCH 256
#define NBATCH 4
#define QB 32
#define KBT 128
#define NTILES (HWA / KBT)   // 32
// q pre-scaled by log2(e) in qkvgemm: exp(s-16) == exp2(s' - SMAXL2)
#define SMAXL2 23.083120654223414f
#define LOG2E  1.4426950408889634f

typedef __attribute__((ext_vector_type(8))) short bf16x8;
typedef __attribute__((ext_vector_type(4))) float f32x4;
typedef __attribute__((ext_vector_type(16))) float f32x16;

__device__ __forceinline__ unsigned short f2bf(float f) {
    union { float f; unsigned u; } a; a.f = f;
    unsigned r = a.u + 0x7FFFu + ((a.u >> 16) & 1u);
    return (unsigned short)(r >> 16);
}
__device__ __forceinline__ float bf2f(unsigned short h) {
    union { unsigned u; float f; } a; a.u = ((unsigned)h) << 16;
    return a.f;
}
__device__ __forceinline__ void bar_lds() {
    asm volatile("s_waitcnt lgkmcnt(0)" ::: "memory");
    __builtin_amdgcn_s_barrier();
}

// ---------------- Stage 0: pack W into A-fragment-ordered bf16 ----------------
__global__ __launch_bounds__(256) void wprep_kernel(
    const float* __restrict__ Wq, const float* __restrict__ bq,
    const float* __restrict__ Wk, const float* __restrict__ bk,
    const float* __restrict__ Wv, const float* __restrict__ bv,
    unsigned short* __restrict__ whi, float* __restrict__ bias_all)
{
    const int ot = blockIdx.x;
    const int t = threadIdx.x;
    const int lane = t & 63;
    const int l15 = lane & 15, g = lane >> 4;
    const int och = ot * 16 + l15;
    #pragma unroll
    for (int pass = 0; pass < 2; ++pass) {
        const int kf = (t >> 6) + 4 * pass;
        unsigned short h8[8];
        #pragma unroll
        for (int j = 0; j < 8; ++j) {
            int c = 32 * kf + g * 8 + j;
            float v;
            if (och < 32)      v = Wq[och * CCH + c];
            else if (och < 64) v = Wk[(och - 32) * CCH + c];
            else               v = Wv[(och - 64) * CCH + c];
            h8[j] = f2bf(v);
        }
        size_t base = ((size_t)(ot * 8 + kf) * 64 + lane) * 8;
        *(bf16x8*)(whi + base) = *(bf16x8*)h8;
    }
    if (ot == 0) {
        for (int i = t; i < 320; i += 256)
            bias_all[i] = (i < 32) ? bq[i] : (i < 64) ? bk[i - 32] : bv[i - 64];
    }
}

// ---------------- Stage 1: MFMA projection GEMM (1-term bf16) ----------------
__global__ __launch_bounds__(256) void qkvgemm_kernel(
    const float* __restrict__ x,
    const unsigned short* __restrict__ whi,
    const float* __restrict__ bias_all,
    unsigned short* __restrict__ qb, unsigned short* __restrict__ kb,
    unsigned short* __restrict__ vb)
{
    const int t = threadIdx.x;
    const int w = t >> 6, l = t & 63, l15 = l & 15, g = l >> 4;
    const int b = blockIdx.x;
    const int logical = (b & 7) * 64 + (b >> 3);
    const int n    = logical >> 7;
    const int rem  = logical & 127;
    const int cb   = rem >> 1;
    const int half = rem & 1;
    const int col = cb * 64 + w * 16 + l15;

    bf16x8 Bh[8];
    #pragma unroll
    for (int kf = 0; kf < 8; ++kf) {
        unsigned short hh[8];
        #pragma unroll
        for (int j = 0; j < 8; ++j)
            hh[j] = f2bf(x[((size_t)(n * CCH + 32 * kf + g * 8 + j)) * HWA + col]);
        Bh[kf] = *(bf16x8*)hh;
    }

    const f32x4 zero4 = {0.f, 0.f, 0.f, 0.f};
    for (int ot = half * 10; ot < half * 10 + 10; ++ot) {
        f32x4 acc = zero4;
        #pragma unroll
        for (int kf = 0; kf < 8; ++kf) {
            bf16x8 Ah = *(const bf16x8*)(whi + ((size_t)(ot * 8 + kf) * 64 + l) * 8);
            acc = __builtin_amdgcn_mfma_f32_16x16x32_bf16(Ah, Bh[kf], acc, 0, 0, 0);
        }
        f32x4 bia = *(const f32x4*)&bias_all[ot * 16 + 4 * g];
        float vv[4];
        #pragma unroll
        for (int r = 0; r < 4; ++r) vv[r] = acc[r] + bia[r];

        if (ot < 4) {
            if (ot < 2) {
                #pragma unroll
                for (int r = 0; r < 4; ++r) vv[r] *= LOG2E;
            }
            unsigned short h4[4];
            #pragma unroll
            for (int r = 0; r < 4; ++r) h4[r] = f2bf(vv[r]);
            unsigned short* hp = (ot < 2) ? qb : kb;
            size_t base = ((size_t)(n * HWA + col)) * 32 + (ot & 1) * 16 + 4 * g;
            *(ushort4*)(hp + base) = *(ushort4*)h4;
        } else {
            #pragma unroll
            for (int r = 0; r < 4; ++r)
                vb[((size_t)(n * CCH + ot * 16 - 64 + 4 * g + r)) * HWA + col] = f2bf(vv[r]);
        }
    }
}

// ---------------- Stage 2: producer/consumer 32x32-PV attention, QB=32 ----------------
// Grid 512 (XCD-swizzled) = 2 blocks/CU (8 waves/SIMD): the occupancy
// doubling, valid now because per-wave state is tiny (VGPR<=64, LDS 50KB).
// Waves 0-7: QK (k-slice 16w) + exp/pack 8/tile; waves 8-15: PV (exclusive
// 32 channels, single q-half of 32, 8x mfma_32x32x16/tile). Structure
// otherwise identical to R19 (passed).
__global__ __launch_bounds__(1024, 4) void attn_kernel(
    const unsigned short* __restrict__ qg, const unsigned short* __restrict__ kg,
    const unsigned short* __restrict__ vg, const float* __restrict__ x,
    const float* __restrict__ gamma_p, float* __restrict__ out)
{
    __shared__ char P_raw[2][8192];        // 8 frags x 1KB per buffer
    __shared__ float lsum_lds[32][9];
    __shared__ float out_lds[32][257];

    const int tid = threadIdx.x;
    const int w = tid >> 6;          // 0..15
    const int l = tid & 63;
    const int l15 = l & 15;
    const int g = l >> 4;
    const bool isqk = (w < 8);
    const int cg = w & 7;            // PV channel group

    const int bid = blockIdx.x;
    const int logical = (bid & 7) * 64 + (bid >> 3);
    const int n  = logical >> 7;
    const int qb = logical & 127;
    const int q0 = qb * QB;

    bf16x8 Qh[2];
    if (isqk) {
        #pragma unroll
        for (int nt = 0; nt < 2; ++nt)
            Qh[nt] = *(const bf16x8*)(qg + ((size_t)(n * HWA + q0 + 16 * nt + l15)) * 32 + g * 8);
    }

    const unsigned short* kbase = kg + ((size_t)(n * HWA + 16 * (w & 7) + l15)) * 32 + g * 8;
    const unsigned short* vbase = vg + ((size_t)(n * CCH + 32 * cg + (l & 31))) * HWA + (l >> 5) * 8;

    f32x16 accA = {};                // D[q32=(r&3)+8*(r>>2)+4*(l>>5)][c=32cg+(l&31)]
    f32x4 s_acc[2];
    float lsum[2] = {0.f, 0.f};
    const f32x4 zero4 = {0.f, 0.f, 0.f, 0.f};

    bf16x8 Kch;                      // next-tile K (QK waves)
    bf16x8 Vc[8];                    // V B-frags (PV waves), reloaded per-slot

    // exp + pack one q16-slice nt into wrb; frag index = w (8 frags, 32q total)
    auto expPack = [&](char* wrb, int nt) {
        float e0 = __builtin_amdgcn_exp2f(s_acc[nt][0] - SMAXL2);
        float e1 = __builtin_amdgcn_exp2f(s_acc[nt][1] - SMAXL2);
        float e2 = __builtin_amdgcn_exp2f(s_acc[nt][2] - SMAXL2);
        float e3 = __builtin_amdgcn_exp2f(s_acc[nt][3] - SMAXL2);
        lsum[nt] += (e0 + e1) + (e2 + e3);
        __hip_bfloat162 b01 = __float22bfloat162_rn(make_float2(e0, e1));
        __hip_bfloat162 b23 = __float22bfloat162_rn(make_float2(e2, e3));
        char* pbp = wrb + (w << 10) +
                    ((((g >> 1) << 5) | ((nt & 1) << 4) | l15) << 4) + (g & 1) * 8;
        *(uint2*)pbp = make_uint2(*(unsigned*)&b01, *(unsigned*)&b23);
    };

    // ---- prologue ----
    if (isqk) {
        bf16x8 k0 = *(const bf16x8*)kbase;
        #pragma unroll
        for (int nt = 0; nt < 2; ++nt)
            s_acc[nt] = __builtin_amdgcn_mfma_f32_16x16x32_bf16(k0, Qh[nt], zero4, 0, 0, 0);
        asm volatile("global_load_dwordx4 %0, %1, off" : "=v"(Kch) : "v"(kbase + (size_t)KBT * 32));
        #pragma unroll
        for (int nt = 0; nt < 2; ++nt) expPack((char*)P_raw[0], nt);
    } else {
        #pragma unroll
        for (int ks = 0; ks < 8; ++ks)
            asm volatile("global_load_dwordx4 %0, %1, off" : "=v"(Vc[ks]) : "v"(vbase + ks * 16));
    }
    bar_lds();                       // P(0) visible

    // ---- body t=0..30 ----
    for (int t = 0; t < NTILES - 1; ++t) {
        const char* rdb = (const char*)P_raw[t & 1];
        char* wrb = (char*)P_raw[(t & 1) ^ 1];
        asm volatile("s_waitcnt vmcnt(0)" ::: "memory");   // V(t)/K(t+1) arrived
        __builtin_amdgcn_sched_barrier(0);

        __builtin_amdgcn_s_setprio(1);
        if (isqk) {
            #pragma unroll
            for (int nt = 0; nt < 2; ++nt)
                s_acc[nt] = __builtin_amdgcn_mfma_f32_16x16x32_bf16(Kch, Qh[nt], zero4, 0, 0, 0);
            int tk = (t + 2 > NTILES - 1) ? NTILES - 1 : t + 2;
            asm volatile("global_load_dwordx4 %0, %1, off"
                         : "=v"(Kch) : "v"(kbase + (size_t)tk * KBT * 32));
            #pragma unroll
            for (int nt = 0; nt < 2; ++nt) expPack(wrb, nt);
        } else {
            const unsigned short* vnext = vbase + (size_t)(t + 1) * KBT;
            bf16x8 a0 = *(const bf16x8*)(rdb + l * 16);
            #pragma unroll
            for (int ks = 0; ks < 8; ++ks) {
                bf16x8 a1 = a0;
                if (ks < 7)
                    a1 = *(const bf16x8*)(rdb + (ks + 1) * 1024 + l * 16);
                accA = __builtin_amdgcn_mfma_f32_32x32x16_bf16(a0, Vc[ks], accA, 0, 0, 0);
                asm volatile("global_load_dwordx4 %0, %1, off" : "=v"(Vc[ks]) : "v"(vnext + ks * 16));
                a0 = a1;
            }
        }
        __builtin_amdgcn_s_setprio(0);
        bar_lds();                   // P(t+1) visible / rdb reads done
    }

    // ---- epilogue: PV(31) with P_raw[1], V(31) ----
    asm volatile("s_waitcnt vmcnt(0)" ::: "memory");
    __builtin_amdgcn_sched_barrier(0);
    if (!isqk) {
        __builtin_amdgcn_s_setprio(1);
        #pragma unroll
        for (int ks = 0; ks < 8; ++ks) {
            bf16x8 AfA = *(const bf16x8*)((const char*)P_raw[1] + ks * 1024 + l * 16);
            accA = __builtin_amdgcn_mfma_f32_32x32x16_bf16(AfA, Vc[ks], accA, 0, 0, 0);
        }
        __builtin_amdgcn_s_setprio(0);
    }

    // lsum: shfl across g then LDS across the 8 QK waves
    if (isqk) {
        #pragma unroll
        for (int nt = 0; nt < 2; ++nt) {
            float s = lsum[nt];
            s += __shfl_xor(s, 16);
            s += __shfl_xor(s, 32);
            lsum[nt] = s;
        }
        if (l < 16) {
            #pragma unroll
            for (int nt = 0; nt < 2; ++nt) lsum_lds[16 * nt + l][w] = lsum[nt];
        }
    }
    bar_lds();

    // out = gamma*(O/l) + x via LDS transpose (PV waves hold O, 32 q rows)
    const float gam = gamma_p[0];
    if (!isqk) {
        #pragma unroll
        for (int r = 0; r < 16; ++r) {
            int q32 = (r & 3) + 8 * (r >> 2) + 4 * (l >> 5);
            out_lds[q32][32 * cg + (l & 31)] = accA[r];
        }
    }
    bar_lds();
    {
        const int q = tid & 31;
        const int crow = tid >> 5;   // 0..31
        float lt = 0.f;
        #pragma unroll
        for (int ww = 0; ww < 8; ++ww) lt += lsum_lds[q][ww];
        const float li = 1.0f / lt;
        #pragma unroll
        for (int p = 0; p < 8; ++p) {
            int c = crow + 32 * p;
            size_t ga = ((size_t)(n * CCH + c)) * HWA + q0 + q;
            out[ga] = gam * out_lds[q][c] * li + x[ga];
        }
    }
}

extern "C" void kernel_launch(void* const* d_in, const int* in_sizes, int n_in,
                              void* d_out, int out_size, void* d_ws, size_t ws_size,
                              hipStream_t stream) {
    const float* x  = (const float*)d_in[0];
    const float* Wq = (const float*)d_in[1];
    const float* bq = (const float*)d_in[2];
    const float* Wk = (const float*)d_in[3];
    const float* bk = (const float*)d_in[4];
    const float* Wv = (const float*)d_in[5];
    const float* bv = (const float*)d_in[6];
    const float* gm = (const float*)d_in[7];
    float* out = (float*)d_out;

    float* bias_all = (float*)d_ws;                               // 320 f
    unsigned short* whi = (unsigned short*)(bias_all + 320);      // 81920
    unsigned short* qbw = whi + 81920;                            // 524288
    unsigned short* kbw = qbw + (size_t)NBATCH * HWA * 32;        // 524288
    unsigned short* vbw = kbw + (size_t)NBATCH * HWA * 32;        // 4,194,304

    hipLaunchKernelGGL(wprep_kernel, dim3(20), dim3(256), 0, stream,
                       Wq, bq, Wk, bk, Wv, bv, whi, bias_all);
    hipLaunchKernelGGL(qkvgemm_kernel, dim3(512), dim3(256), 0, stream,
                       x, whi, bias_all, qbw, kbw, vbw);
    hipLaunchKernelGGL(attn_kernel, dim3(512), dim3(1024), 0, stream,
                       qbw, kbw, vbw, x, gm, out);
}

// Round 21
// 89.578 us; speedup vs baseline: 1.7401x; 1.7401x over previous
//
#include <hip/hip_runtime.h>
#include <hip/hip_bf16.h>

#define HWA 4096
#define CCH 256
#define NBATCH 4
#define QB 64
#define KBT 128
#define NTILES (HWA / KBT)   // 32
// q pre-scaled by log2(e) in qkvgemm: exp(s-16) == exp2(s' - SMAXL2)
#define SMAXL2 23.083120654223414f
#define LOG2E  1.4426950408889634f

typedef __attribute__((ext_vector_type(8))) short bf16x8;
typedef __attribute__((ext_vector_type(4))) float f32x4;
typedef __attribute__((ext_vector_type(16))) float f32x16;

__device__ __forceinline__ unsigned short f2bf(float f) {
    union { float f; unsigned u; } a; a.f = f;
    unsigned r = a.u + 0x7FFFu + ((a.u >> 16) & 1u);
    return (unsigned short)(r >> 16);
}
__device__ __forceinline__ float bf2f(unsigned short h) {
    union { unsigned u; float f; } a; a.u = ((unsigned)h) << 16;
    return a.f;
}
__device__ __forceinline__ void bar_lds() {
    asm volatile("s_waitcnt lgkmcnt(0)" ::: "memory");
    __builtin_amdgcn_s_barrier();
}

// ---------------- Stage 0: pack W into A-fragment-ordered bf16 ----------------
__global__ __launch_bounds__(256) void wprep_kernel(
    const float* __restrict__ Wq, const float* __restrict__ bq,
    const float* __restrict__ Wk, const float* __restrict__ bk,
    const float* __restrict__ Wv, const float* __restrict__ bv,
    unsigned short* __restrict__ whi, float* __restrict__ bias_all)
{
    const int ot = blockIdx.x;
    const int t = threadIdx.x;
    const int lane = t & 63;
    const int l15 = lane & 15, g = lane >> 4;
    const int och = ot * 16 + l15;
    #pragma unroll
    for (int pass = 0; pass < 2; ++pass) {
        const int kf = (t >> 6) + 4 * pass;
        unsigned short h8[8];
        #pragma unroll
        for (int j = 0; j < 8; ++j) {
            int c = 32 * kf + g * 8 + j;
            float v;
            if (och < 32)      v = Wq[och * CCH + c];
            else if (och < 64) v = Wk[(och - 32) * CCH + c];
            else               v = Wv[(och - 64) * CCH + c];
            h8[j] = f2bf(v);
        }
        size_t base = ((size_t)(ot * 8 + kf) * 64 + lane) * 8;
        *(bf16x8*)(whi + base) = *(bf16x8*)h8;
    }
    if (ot == 0) {
        for (int i = t; i < 320; i += 256)
            bias_all[i] = (i < 32) ? bq[i] : (i < 64) ? bk[i - 32] : bv[i - 64];
    }
}

// ---------------- Stage 1: MFMA projection GEMM (1-term bf16) ----------------
// Grid 1024 (XCD-swizzled), 4 waves, 4 blocks/CU; block does a QUARTER of the
// 20 och-tiles (5 each) — doubles TLP on this latency-bound dispatch vs R19.
__global__ __launch_bounds__(256) void qkvgemm_kernel(
    const float* __restrict__ x,
    const unsigned short* __restrict__ whi,
    const float* __restrict__ bias_all,
    unsigned short* __restrict__ qb, unsigned short* __restrict__ kb,
    unsigned short* __restrict__ vb)
{
    const int t = threadIdx.x;
    const int w = t >> 6, l = t & 63, l15 = l & 15, g = l >> 4;
    const int b = blockIdx.x;
    const int logical = (b & 7) * 128 + (b >> 3);
    const int n    = logical >> 8;
    const int rem  = logical & 255;
    const int cb   = rem >> 2;
    const int quarter = rem & 3;
    const int col = cb * 64 + w * 16 + l15;

    bf16x8 Bh[8];
    #pragma unroll
    for (int kf = 0; kf < 8; ++kf) {
        unsigned short hh[8];
        #pragma unroll
        for (int j = 0; j < 8; ++j)
            hh[j] = f2bf(x[((size_t)(n * CCH + 32 * kf + g * 8 + j)) * HWA + col]);
        Bh[kf] = *(bf16x8*)hh;
    }

    const f32x4 zero4 = {0.f, 0.f, 0.f, 0.f};
    for (int ot = quarter * 5; ot < quarter * 5 + 5; ++ot) {
        f32x4 acc = zero4;
        #pragma unroll
        for (int kf = 0; kf < 8; ++kf) {
            bf16x8 Ah = *(const bf16x8*)(whi + ((size_t)(ot * 8 + kf) * 64 + l) * 8);
            acc = __builtin_amdgcn_mfma_f32_16x16x32_bf16(Ah, Bh[kf], acc, 0, 0, 0);
        }
        f32x4 bia = *(const f32x4*)&bias_all[ot * 16 + 4 * g];
        float vv[4];
        #pragma unroll
        for (int r = 0; r < 4; ++r) vv[r] = acc[r] + bia[r];

        if (ot < 4) {
            if (ot < 2) {
                #pragma unroll
                for (int r = 0; r < 4; ++r) vv[r] *= LOG2E;
            }
            unsigned short h4[4];
            #pragma unroll
            for (int r = 0; r < 4; ++r) h4[r] = f2bf(vv[r]);
            unsigned short* hp = (ot < 2) ? qb : kb;
            size_t base = ((size_t)(n * HWA + col)) * 32 + (ot & 1) * 16 + 4 * g;
            *(ushort4*)(hp + base) = *(ushort4*)h4;
        } else {
            #pragma unroll
            for (int r = 0; r < 4; ++r)
                vb[((size_t)(n * CCH + ot * 16 - 64 + 4 * g + r)) * HWA + col] = f2bf(vv[r]);
        }
    }
}

// ---------------- Stage 2: producer/consumer 32x32-PV flash attention ----------------
// EXACT R19 kernel (passed, attn 75.7us): grid 256 XCD-swizzled, 1024 threads.
// Waves 0-7: QK + exp/pack; waves 8-15: PV (exclusive 32 channels, both
// q-halves, 32x32x16 MFMA). 2-deep P, ONE barrier/tile, Af reads pipelined.
__global__ __launch_bounds__(1024, 4) void attn_kernel(
    const unsigned short* __restrict__ qg, const unsigned short* __restrict__ kg,
    const unsigned short* __restrict__ vg, const float* __restrict__ x,
    const float* __restrict__ gamma_p, float* __restrict__ out)
{
    __shared__ char P_raw[2][16384];       // 16 frags x 1KB per buffer
    __shared__ float lsum_lds[64][9];
    __shared__ float out_lds[32][257];

    const int tid = threadIdx.x;
    const int w = tid >> 6;          // 0..15
    const int l = tid & 63;
    const int l15 = l & 15;
    const int g = l >> 4;
    const bool isqk = (w < 8);
    const int cg = w & 7;            // PV channel group

    const int bid = blockIdx.x;
    const int logical = (bid & 7) * 32 + (bid >> 3);
    const int n  = logical >> 6;
    const int qb = logical & 63;
    const int q0 = qb * QB;

    bf16x8 Qh[4];
    if (isqk) {
        #pragma unroll
        for (int nt = 0; nt < 4; ++nt)
            Qh[nt] = *(const bf16x8*)(qg + ((size_t)(n * HWA + q0 + 16 * nt + l15)) * 32 + g * 8);
    }

    const unsigned short* kbase = kg + ((size_t)(n * HWA + 16 * (w & 7) + l15)) * 32 + g * 8;
    const unsigned short* vbase = vg + ((size_t)(n * CCH + 32 * cg + (l & 31))) * HWA + (l >> 5) * 8;

    f32x16 accA = {}, accB = {};
    f32x4 s_acc[4];
    float lsum[4] = {0.f, 0.f, 0.f, 0.f};
    const f32x4 zero4 = {0.f, 0.f, 0.f, 0.f};

    bf16x8 Kch;                      // next-tile K (QK waves)
    bf16x8 Vc[8];                    // V B-frags (PV waves), reloaded per-slot

    auto expPack = [&](char* wrb, int nt) {
        float e0 = __builtin_amdgcn_exp2f(s_acc[nt][0] - SMAXL2);
        float e1 = __builtin_amdgcn_exp2f(s_acc[nt][1] - SMAXL2);
        float e2 = __builtin_amdgcn_exp2f(s_acc[nt][2] - SMAXL2);
        float e3 = __builtin_amdgcn_exp2f(s_acc[nt][3] - SMAXL2);
        lsum[nt] += (e0 + e1) + (e2 + e3);
        __hip_bfloat162 b01 = __float22bfloat162_rn(make_float2(e0, e1));
        __hip_bfloat162 b23 = __float22bfloat162_rn(make_float2(e2, e3));
        char* pbp = wrb + (((nt >> 1) * 8 + w) << 10) +
                    ((((g >> 1) << 5) | ((nt & 1) << 4) | l15) << 4) + (g & 1) * 8;
        *(uint2*)pbp = make_uint2(*(unsigned*)&b01, *(unsigned*)&b23);
    };

    // ---- prologue ----
    if (isqk) {
        bf16x8 k0 = *(const bf16x8*)kbase;
        #pragma unroll
        for (int nt = 0; nt < 4; ++nt)
            s_acc[nt] = __builtin_amdgcn_mfma_f32_16x16x32_bf16(k0, Qh[nt], zero4, 0, 0, 0);
        asm volatile("global_load_dwordx4 %0, %1, off" : "=v"(Kch) : "v"(kbase + (size_t)KBT * 32));
        #pragma unroll
        for (int nt = 0; nt < 4; ++nt) expPack((char*)P_raw[0], nt);
    } else {
        #pragma unroll
        for (int ks = 0; ks < 8; ++ks)
            asm volatile("global_load_dwordx4 %0, %1, off" : "=v"(Vc[ks]) : "v"(vbase + ks * 16));
    }
    bar_lds();                       // P(0) visible

    // ---- body t=0..30 ----
    for (int t = 0; t < NTILES - 1; ++t) {
        const char* rdb = (const char*)P_raw[t & 1];
        char* wrb = (char*)P_raw[(t & 1) ^ 1];
        asm volatile("s_waitcnt vmcnt(0)" ::: "memory");   // V(t)/K(t+1) arrived
        __builtin_amdgcn_sched_barrier(0);

        __builtin_amdgcn_s_setprio(1);
        if (isqk) {
            #pragma unroll
            for (int nt = 0; nt < 4; ++nt)
                s_acc[nt] = __builtin_amdgcn_mfma_f32_16x16x32_bf16(Kch, Qh[nt], zero4, 0, 0, 0);
            int tk = (t + 2 > NTILES - 1) ? NTILES - 1 : t + 2;
            asm volatile("global_load_dwordx4 %0, %1, off"
                         : "=v"(Kch) : "v"(kbase + (size_t)tk * KBT * 32));
            #pragma unroll
            for (int nt = 0; nt < 4; ++nt) expPack(wrb, nt);
        } else {
            const unsigned short* vnext = vbase + (size_t)(t + 1) * KBT;
            bf16x8 a0 = *(const bf16x8*)(rdb + l * 16);
            bf16x8 b0 = *(const bf16x8*)(rdb + 8 * 1024 + l * 16);
            #pragma unroll
            for (int ks = 0; ks < 8; ++ks) {
                bf16x8 a1 = a0, b1 = b0;
                if (ks < 7) {
                    a1 = *(const bf16x8*)(rdb + (ks + 1) * 1024 + l * 16);
                    b1 = *(const bf16x8*)(rdb + (9 + ks) * 1024 + l * 16);
                }
                accA = __builtin_amdgcn_mfma_f32_32x32x16_bf16(a0, Vc[ks], accA, 0, 0, 0);
                accB = __builtin_amdgcn_mfma_f32_32x32x16_bf16(b0, Vc[ks], accB, 0, 0, 0);
                asm volatile("global_load_dwordx4 %0, %1, off" : "=v"(Vc[ks]) : "v"(vnext + ks * 16));
                a0 = a1; b0 = b1;
            }
        }
        __builtin_amdgcn_s_setprio(0);
        bar_lds();                   // P(t+1) visible / rdb reads done
    }

    // ---- epilogue: PV(31) with P_raw[1], V(31) ----
    asm volatile("s_waitcnt vmcnt(0)" ::: "memory");
    __builtin_amdgcn_sched_barrier(0);
    if (!isqk) {
        __builtin_amdgcn_s_setprio(1);
        #pragma unroll
        for (int ks = 0; ks < 8; ++ks) {
            bf16x8 AfA = *(const bf16x8*)((const char*)P_raw[1] + ks * 1024 + l * 16);
            bf16x8 AfB = *(const bf16x8*)((const char*)P_raw[1] + (8 + ks) * 1024 + l * 16);
            accA = __builtin_amdgcn_mfma_f32_32x32x16_bf16(AfA, Vc[ks], accA, 0, 0, 0);
            accB = __builtin_amdgcn_mfma_f32_32x32x16_bf16(AfB, Vc[ks], accB, 0, 0, 0);
        }
        __builtin_amdgcn_s_setprio(0);
    }

    // lsum: shfl across g then LDS across the 8 QK waves
    if (isqk) {
        #pragma unroll
        for (int nt = 0; nt < 4; ++nt) {
            float s = lsum[nt];
            s += __shfl_xor(s, 16);
            s += __shfl_xor(s, 32);
            lsum[nt] = s;
        }
        if (l < 16) {
            #pragma unroll
            for (int nt = 0; nt < 4; ++nt) lsum_lds[16 * nt + l][w] = lsum[nt];
        }
    }
    bar_lds();

    // out = gamma*(O/l) + x per q-half via LDS transpose (PV waves hold O)
    const float gam = gamma_p[0];
    for (int qq = 0; qq < 2; ++qq) {
        if (!isqk) {
            const f32x16& a = qq ? accB : accA;
            #pragma unroll
            for (int r = 0; r < 16; ++r) {
                int q32 = (r & 3) + 8 * (r >> 2) + 4 * (l >> 5);
                out_lds[q32][32 * cg + (l & 31)] = a[r];
            }
        }
        bar_lds();
        const int q = tid & 31;
        const int crow = tid >> 5;   // 0..31
        float lt = 0.f;
        #pragma unroll
        for (int ww = 0; ww < 8; ++ww) lt += lsum_lds[qq * 32 + q][ww];
        const float li = 1.0f / lt;
        #pragma unroll
        for (int p = 0; p < 8; ++p) {
            int c = crow + 32 * p;
            size_t ga = ((size_t)(n * CCH + c)) * HWA + q0 + qq * 32 + q;
            out[ga] = gam * out_lds[q][c] * li + x[ga];
        }
        bar_lds();
    }
}

extern "C" void kernel_launch(void* const* d_in, const int* in_sizes, int n_in,
                              void* d_out, int out_size, void* d_ws, size_t ws_size,
                              hipStream_t stream) {
    const float* x  = (const float*)d_in[0];
    const float* Wq = (const float*)d_in[1];
    const float* bq = (const float*)d_in[2];
    const float* Wk = (const float*)d_in[3];
    const float* bk = (const float*)d_in[4];
    const float* Wv = (const float*)d_in[5];
    const float* bv = (const float*)d_in[6];
    const float* gm = (const float*)d_in[7];
    float* out = (float*)d_out;

    float* bias_all = (float*)d_ws;                               // 320 f
    unsigned short* whi = (unsigned short*)(bias_all + 320);      // 81920
    unsigned short* qbw = whi + 81920;                            // 524288
    unsigned short* kbw = qbw + (size_t)NBATCH * HWA * 32;        // 524288
    unsigned short* vbw = kbw + (size_t)NBATCH * HWA * 32;        // 4,194,304

    hipLaunchKernelGGL(wprep_kernel, dim3(20), dim3(256), 0, stream,
                       Wq, bq, Wk, bk, Wv, bv, whi, bias_all);
    hipLaunchKernelGGL(qkvgemm_kernel, dim3(1024), dim3(256), 0, stream,
                       x, whi, bias_all, qbw, kbw, vbw);
    hipLaunchKernelGGL(attn_kernel, dim3(256), dim3(1024), 0, stream,
                       qbw, kbw, vbw, x, gm, out);
}

// Round 22
// 89.366 us; speedup vs baseline: 1.7442x; 1.0024x over previous
//
#include <hip/hip_runtime.h>
#include <hip/hip_bf16.h>

#define HWA 4096
#define CCH 256
#define NBATCH 4
#define QB 64
#define KBT 128
#define NTILES (HWA / KBT)   // 32
// q pre-scaled by log2(e) in qkvgemm: exp(s-16) == exp2(s' - SMAXL2)
#define SMAXL2 23.083120654223414f
#define LOG2E  1.4426950408889634f

typedef __attribute__((ext_vector_type(8))) short bf16x8;
typedef __attribute__((ext_vector_type(4))) float f32x4;
typedef __attribute__((ext_vector_type(16))) float f32x16;

__device__ __forceinline__ unsigned short f2bf(float f) {
    union { float f; unsigned u; } a; a.f = f;
    unsigned r = a.u + 0x7FFFu + ((a.u >> 16) & 1u);
    return (unsigned short)(r >> 16);
}
__device__ __forceinline__ float bf2f(unsigned short h) {
    union { unsigned u; float f; } a; a.u = ((unsigned)h) << 16;
    return a.f;
}
__device__ __forceinline__ void bar_lds() {
    asm volatile("s_waitcnt lgkmcnt(0)" ::: "memory");
    __builtin_amdgcn_s_barrier();
}

// ---------------- Stage 0: pack W into A-fragment-ordered bf16 ----------------
__global__ __launch_bounds__(256) void wprep_kernel(
    const float* __restrict__ Wq, const float* __restrict__ bq,
    const float* __restrict__ Wk, const float* __restrict__ bk,
    const float* __restrict__ Wv, const float* __restrict__ bv,
    unsigned short* __restrict__ whi, float* __restrict__ bias_all)
{
    const int ot = blockIdx.x;
    const int t = threadIdx.x;
    const int lane = t & 63;
    const int l15 = lane & 15, g = lane >> 4;
    const int och = ot * 16 + l15;
    #pragma unroll
    for (int pass = 0; pass < 2; ++pass) {
        const int kf = (t >> 6) + 4 * pass;
        unsigned short h8[8];
        #pragma unroll
        for (int j = 0; j < 8; ++j) {
            int c = 32 * kf + g * 8 + j;
            float v;
            if (och < 32)      v = Wq[och * CCH + c];
            else if (och < 64) v = Wk[(och - 32) * CCH + c];
            else               v = Wv[(och - 64) * CCH + c];
            h8[j] = f2bf(v);
        }
        size_t base = ((size_t)(ot * 8 + kf) * 64 + lane) * 8;
        *(bf16x8*)(whi + base) = *(bf16x8*)h8;
    }
    if (ot == 0) {
        for (int i = t; i < 320; i += 256)
            bias_all[i] = (i < 32) ? bq[i] : (i < 64) ? bk[i - 32] : bv[i - 64];
    }
}

// ---------------- Stage 1: MFMA projection GEMM (1-term bf16) ----------------
// Grid 1024 (XCD-swizzled), 4 waves, 4 blocks/CU; block does a QUARTER of the
// 20 och-tiles (5 each).
__global__ __launch_bounds__(256) void qkvgemm_kernel(
    const float* __restrict__ x,
    const unsigned short* __restrict__ whi,
    const float* __restrict__ bias_all,
    unsigned short* __restrict__ qb, unsigned short* __restrict__ kb,
    unsigned short* __restrict__ vb)
{
    const int t = threadIdx.x;
    const int w = t >> 6, l = t & 63, l15 = l & 15, g = l >> 4;
    const int b = blockIdx.x;
    const int logical = (b & 7) * 128 + (b >> 3);
    const int n    = logical >> 8;
    const int rem  = logical & 255;
    const int cb   = rem >> 2;
    const int quarter = rem & 3;
    const int col = cb * 64 + w * 16 + l15;

    bf16x8 Bh[8];
    #pragma unroll
    for (int kf = 0; kf < 8; ++kf) {
        unsigned short hh[8];
        #pragma unroll
        for (int j = 0; j < 8; ++j)
            hh[j] = f2bf(x[((size_t)(n * CCH + 32 * kf + g * 8 + j)) * HWA + col]);
        Bh[kf] = *(bf16x8*)hh;
    }

    const f32x4 zero4 = {0.f, 0.f, 0.f, 0.f};
    for (int ot = quarter * 5; ot < quarter * 5 + 5; ++ot) {
        f32x4 acc = zero4;
        #pragma unroll
        for (int kf = 0; kf < 8; ++kf) {
            bf16x8 Ah = *(const bf16x8*)(whi + ((size_t)(ot * 8 + kf) * 64 + l) * 8);
            acc = __builtin_amdgcn_mfma_f32_16x16x32_bf16(Ah, Bh[kf], acc, 0, 0, 0);
        }
        f32x4 bia = *(const f32x4*)&bias_all[ot * 16 + 4 * g];
        float vv[4];
        #pragma unroll
        for (int r = 0; r < 4; ++r) vv[r] = acc[r] + bia[r];

        if (ot < 4) {
            if (ot < 2) {
                #pragma unroll
                for (int r = 0; r < 4; ++r) vv[r] *= LOG2E;
            }
            unsigned short h4[4];
            #pragma unroll
            for (int r = 0; r < 4; ++r) h4[r] = f2bf(vv[r]);
            unsigned short* hp = (ot < 2) ? qb : kb;
            size_t base = ((size_t)(n * HWA + col)) * 32 + (ot & 1) * 16 + 4 * g;
            *(ushort4*)(hp + base) = *(ushort4*)h4;
        } else {
            #pragma unroll
            for (int r = 0; r < 4; ++r)
                vb[((size_t)(n * CCH + ot * 16 - 64 + 4 * g + r)) * HWA + col] = f2bf(vv[r]);
        }
    }
}

// ---------------- Stage 2: producer/consumer 32x32-PV flash attention ----------------
// R19 structure; ONE change: PV waves use per-slot counted vmcnt(7) instead of
// a tile-top vmcnt(0) drain. Ledger: at slot ks, outstanding = (8-ks) V(t)
// loads + ks V(t+1) loads = 8; retiring load ks => allow 7. The wave never
// drains in the loop (T4). sched_barrier(0) after each wait (rule #18).
__global__ __launch_bounds__(1024, 4) void attn_kernel(
    const unsigned short* __restrict__ qg, const unsigned short* __restrict__ kg,
    const unsigned short* __restrict__ vg, const float* __restrict__ x,
    const float* __restrict__ gamma_p, float* __restrict__ out)
{
    __shared__ char P_raw[2][16384];       // 16 frags x 1KB per buffer
    __shared__ float lsum_lds[64][9];
    __shared__ float out_lds[32][257];

    const int tid = threadIdx.x;
    const int w = tid >> 6;          // 0..15
    const int l = tid & 63;
    const int l15 = l & 15;
    const int g = l >> 4;
    const bool isqk = (w < 8);
    const int cg = w & 7;            // PV channel group

    const int bid = blockIdx.x;
    const int logical = (bid & 7) * 32 + (bid >> 3);
    const int n  = logical >> 6;
    const int qb = logical & 63;
    const int q0 = qb * QB;

    bf16x8 Qh[4];
    if (isqk) {
        #pragma unroll
        for (int nt = 0; nt < 4; ++nt)
            Qh[nt] = *(const bf16x8*)(qg + ((size_t)(n * HWA + q0 + 16 * nt + l15)) * 32 + g * 8);
    }

    const unsigned short* kbase = kg + ((size_t)(n * HWA + 16 * (w & 7) + l15)) * 32 + g * 8;
    const unsigned short* vbase = vg + ((size_t)(n * CCH + 32 * cg + (l & 31))) * HWA + (l >> 5) * 8;

    f32x16 accA = {}, accB = {};
    f32x4 s_acc[4];
    float lsum[4] = {0.f, 0.f, 0.f, 0.f};
    const f32x4 zero4 = {0.f, 0.f, 0.f, 0.f};

    bf16x8 Kch;                      // next-tile K (QK waves)
    bf16x8 Vc[8];                    // V B-frags (PV waves), reloaded per-slot

    auto expPack = [&](char* wrb, int nt) {
        float e0 = __builtin_amdgcn_exp2f(s_acc[nt][0] - SMAXL2);
        float e1 = __builtin_amdgcn_exp2f(s_acc[nt][1] - SMAXL2);
        float e2 = __builtin_amdgcn_exp2f(s_acc[nt][2] - SMAXL2);
        float e3 = __builtin_amdgcn_exp2f(s_acc[nt][3] - SMAXL2);
        lsum[nt] += (e0 + e1) + (e2 + e3);
        __hip_bfloat162 b01 = __float22bfloat162_rn(make_float2(e0, e1));
        __hip_bfloat162 b23 = __float22bfloat162_rn(make_float2(e2, e3));
        char* pbp = wrb + (((nt >> 1) * 8 + w) << 10) +
                    ((((g >> 1) << 5) | ((nt & 1) << 4) | l15) << 4) + (g & 1) * 8;
        *(uint2*)pbp = make_uint2(*(unsigned*)&b01, *(unsigned*)&b23);
    };

    // ---- prologue ----
    if (isqk) {
        bf16x8 k0 = *(const bf16x8*)kbase;
        #pragma unroll
        for (int nt = 0; nt < 4; ++nt)
            s_acc[nt] = __builtin_amdgcn_mfma_f32_16x16x32_bf16(k0, Qh[nt], zero4, 0, 0, 0);
        asm volatile("global_load_dwordx4 %0, %1, off" : "=v"(Kch) : "v"(kbase + (size_t)KBT * 32));
        #pragma unroll
        for (int nt = 0; nt < 4; ++nt) expPack((char*)P_raw[0], nt);
    } else {
        #pragma unroll
        for (int ks = 0; ks < 8; ++ks)
            asm volatile("global_load_dwordx4 %0, %1, off" : "=v"(Vc[ks]) : "v"(vbase + ks * 16));
    }
    bar_lds();                       // P(0) visible

    // ---- body t=0..30 ----
    for (int t = 0; t < NTILES - 1; ++t) {
        const char* rdb = (const char*)P_raw[t & 1];
        char* wrb = (char*)P_raw[(t & 1) ^ 1];

        __builtin_amdgcn_s_setprio(1);
        if (isqk) {
            asm volatile("s_waitcnt vmcnt(0)" ::: "memory");   // K(t+1) (issued 1 tile ago)
            __builtin_amdgcn_sched_barrier(0);
            #pragma unroll
            for (int nt = 0; nt < 4; ++nt)
                s_acc[nt] = __builtin_amdgcn_mfma_f32_16x16x32_bf16(Kch, Qh[nt], zero4, 0, 0, 0);
            int tk = (t + 2 > NTILES - 1) ? NTILES - 1 : t + 2;
            asm volatile("global_load_dwordx4 %0, %1, off"
                         : "=v"(Kch) : "v"(kbase + (size_t)tk * KBT * 32));
            #pragma unroll
            for (int nt = 0; nt < 4; ++nt) expPack(wrb, nt);
        } else {
            const unsigned short* vnext = vbase + (size_t)(t + 1) * KBT;
            bf16x8 a0 = *(const bf16x8*)(rdb + l * 16);
            bf16x8 b0 = *(const bf16x8*)(rdb + 8 * 1024 + l * 16);
            #pragma unroll
            for (int ks = 0; ks < 8; ++ks) {
                // counted wait: retire exactly V(t) slot ks; 7 stay in flight
                asm volatile("s_waitcnt vmcnt(7)" ::: "memory");
                __builtin_amdgcn_sched_barrier(0);
                bf16x8 a1 = a0, b1 = b0;
                if (ks < 7) {
                    a1 = *(const bf16x8*)(rdb + (ks + 1) * 1024 + l * 16);
                    b1 = *(const bf16x8*)(rdb + (9 + ks) * 1024 + l * 16);
                }
                accA = __builtin_amdgcn_mfma_f32_32x32x16_bf16(a0, Vc[ks], accA, 0, 0, 0);
                accB = __builtin_amdgcn_mfma_f32_32x32x16_bf16(b0, Vc[ks], accB, 0, 0, 0);
                asm volatile("global_load_dwordx4 %0, %1, off" : "=v"(Vc[ks]) : "v"(vnext + ks * 16));
                a0 = a1; b0 = b1;
            }
        }
        __builtin_amdgcn_s_setprio(0);
        bar_lds();                   // P(t+1) visible / rdb reads done
    }

    // ---- epilogue: PV(31) with P_raw[1], V(31) ----
    asm volatile("s_waitcnt vmcnt(0)" ::: "memory");
    __builtin_amdgcn_sched_barrier(0);
    if (!isqk) {
        __builtin_amdgcn_s_setprio(1);
        #pragma unroll
        for (int ks = 0; ks < 8; ++ks) {
            bf16x8 AfA = *(const bf16x8*)((const char*)P_raw[1] + ks * 1024 + l * 16);
            bf16x8 AfB = *(const bf16x8*)((const char*)P_raw[1] + (8 + ks) * 1024 + l * 16);
            accA = __builtin_amdgcn_mfma_f32_32x32x16_bf16(AfA, Vc[ks], accA, 0, 0, 0);
            accB = __builtin_amdgcn_mfma_f32_32x32x16_bf16(AfB, Vc[ks], accB, 0, 0, 0);
        }
        __builtin_amdgcn_s_setprio(0);
    }

    // lsum: shfl across g then LDS across the 8 QK waves
    if (isqk) {
        #pragma unroll
        for (int nt = 0; nt < 4; ++nt) {
            float s = lsum[nt];
            s += __shfl_xor(s, 16);
            s += __shfl_xor(s, 32);
            lsum[nt] = s;
        }
        if (l < 16) {
            #pragma unroll
            for (int nt = 0; nt < 4; ++nt) lsum_lds[16 * nt + l][w] = lsum[nt];
        }
    }
    bar_lds();

    // out = gamma*(O/l) + x per q-half via LDS transpose (PV waves hold O)
    const float gam = gamma_p[0];
    for (int qq = 0; qq < 2; ++qq) {
        if (!isqk) {
            const f32x16& a = qq ? accB : accA;
            #pragma unroll
            for (int r = 0; r < 16; ++r) {
                int q32 = (r & 3) + 8 * (r >> 2) + 4 * (l >> 5);
                out_lds[q32][32 * cg + (l & 31)] = a[r];
            }
        }
        bar_lds();
        const int q = tid & 31;
        const int crow = tid >> 5;   // 0..31
        float lt = 0.f;
        #pragma unroll
        for (int ww = 0; ww < 8; ++ww) lt += lsum_lds[qq * 32 + q][ww];
        const float li = 1.0f / lt;
        #pragma unroll
        for (int p = 0; p < 8; ++p) {
            int c = crow + 32 * p;
            size_t ga = ((size_t)(n * CCH + c)) * HWA + q0 + qq * 32 + q;
            out[ga] = gam * out_lds[q][c] * li + x[ga];
        }
        bar_lds();
    }
}

extern "C" void kernel_launch(void* const* d_in, const int* in_sizes, int n_in,
                              void* d_out, int out_size, void* d_ws, size_t ws_size,
                              hipStream_t stream) {
    const float* x  = (const float*)d_in[0];
    const float* Wq = (const float*)d_in[1];
    const float* bq = (const float*)d_in[2];
    const float* Wk = (const float*)d_in[3];
    const float* bk = (const float*)d_in[4];
    const float* Wv = (const float*)d_in[5];
    const float* bv = (const float*)d_in[6];
    const float* gm = (const float*)d_in[7];
    float* out = (float*)d_out;

    float* bias_all = (float*)d_ws;                               // 320 f
    unsigned short* whi = (unsigned short*)(bias_all + 320);      // 81920
    unsigned short* qbw = whi + 81920;                            // 524288
    unsigned short* kbw = qbw + (size_t)NBATCH * HWA * 32;        // 524288
    unsigned short* vbw = kbw + (size_t)NBATCH * HWA * 32;        // 4,194,304

    hipLaunchKernelGGL(wprep_kernel, dim3(20), dim3(256), 0, stream,
                       Wq, bq, Wk, bk, Wv, bv, whi, bias_all);
    hipLaunchKernelGGL(qkvgemm_kernel, dim3(1024), dim3(256), 0, stream,
                       x, whi, bias_all, qbw, kbw, vbw);
    hipLaunchKernelGGL(attn_kernel, dim3(256), dim3(1024), 0, stream,
                       qbw, kbw, vbw, x, gm, out);
}